// Round 1
// baseline (444.794 us; speedup 1.0000x reference)
//
#include <hip/hip_runtime.h>

typedef unsigned short u16;
typedef __attribute__((ext_vector_type(8))) short short8;
typedef __attribute__((ext_vector_type(4))) float f32x4;
typedef __attribute__((ext_vector_type(4))) u16 u16x4;

#define NPT 128
#define DIM 512
#define KT 48
#define KC 32

__device__ __forceinline__ u16 f2bf(float f) {
    unsigned u = __builtin_bit_cast(unsigned, f);
    return (u16)((u + 0x7FFFu + ((u >> 16) & 1u)) >> 16);
}

// Fold BN into clusters: cTs[k][d] = bf16(clusters[d][k] * s_k), t[k] = b_k - rm_k*s_k
__global__ void prep_kernel(const float* __restrict__ clusters,
                            const float* __restrict__ bn_w,
                            const float* __restrict__ bn_b,
                            const float* __restrict__ bn_rm,
                            const float* __restrict__ bn_rv,
                            u16* __restrict__ cTs,
                            float* __restrict__ tvec) {
    const int k = blockIdx.x;
    const float s = bn_w[k] * rsqrtf(bn_rv[k] + 1e-5f);
    if (threadIdx.x == 0) tvec[k] = bn_b[k] - bn_rm[k] * s;
    for (int d = threadIdx.x; d < DIM; d += blockDim.x)
        cTs[k * DIM + d] = f2bf(clusters[d * KT + k] * s);
}

__global__ __launch_bounds__(512)
void vlad_kernel(const float* __restrict__ x,
                 const float* __restrict__ c2,     // [512][32] fp32
                 const u16* __restrict__ cTs,      // [48][512] bf16
                 const float* __restrict__ tvec,   // [48]
                 float* __restrict__ out) {
    __shared__ __align__(16) u16 xs[NPT * DIM];    // 128 KB, swizzled row-major
    __shared__ __align__(16) u16 aT[KC][136];      // assignment^T, padded
    __shared__ float t_s[KT];
    __shared__ float asum_part[8][KC];
    __shared__ float asum_s[KC];
    __shared__ float colsq_part[8][KC];
    __shared__ float scalek[KC];

    const int b    = blockIdx.x;
    const int tid  = threadIdx.x;
    const int wave = tid >> 6;
    const int lane = tid & 63;
    const int lr   = lane & 15;
    const int lg   = lane >> 4;

    if (tid < KT) t_s[tid] = tvec[tid];

    // ---- stage x_b -> bf16 LDS (swizzle: byte ^= (n&7)<<4) ----
    {
        const f32x4* gx = (const f32x4*)(x + (size_t)b * (NPT * DIM));
        #pragma unroll 4
        for (int it = 0; it < 32; ++it) {
            int c = tid + it * 512;          // chunk of 4 floats
            f32x4 v = gx[c];
            int n  = c >> 7;                 // row
            int d0 = (c & 127) << 2;         // col
            u16x4 w;
            w[0] = f2bf(v[0]); w[1] = f2bf(v[1]); w[2] = f2bf(v[2]); w[3] = f2bf(v[3]);
            int byteoff = n * 1024 + ((2 * d0) ^ ((n & 7) << 4));
            *(u16x4*)((char*)xs + byteoff) = w;
        }
    }
    __syncthreads();

    // ---- phase 1: logits[128][48] = x @ cTs^T, wave w owns rows w*16..w*16+15 ----
    f32x4 acc0 = {0.f,0.f,0.f,0.f}, acc1 = {0.f,0.f,0.f,0.f}, acc2 = {0.f,0.f,0.f,0.f};
    {
        const int nrow = wave * 16 + lr;
        const int rowbase = nrow * 1024;
        const int sw = (nrow & 7) << 4;
        #pragma unroll 2
        for (int step = 0; step < 16; ++step) {
            const int d0 = step * 32 + lg * 8;
            short8 af = *(const short8*)((const char*)xs + (rowbase + ((2 * d0) ^ sw)));
            short8 b0 = *(const short8*)(cTs + (0 * 16 + lr) * DIM + d0);
            short8 b1 = *(const short8*)(cTs + (1 * 16 + lr) * DIM + d0);
            short8 b2 = *(const short8*)(cTs + (2 * 16 + lr) * DIM + d0);
            acc0 = __builtin_amdgcn_mfma_f32_16x16x32_bf16(af, b0, acc0, 0, 0, 0);
            acc1 = __builtin_amdgcn_mfma_f32_16x16x32_bf16(af, b1, acc1, 0, 0, 0);
            acc2 = __builtin_amdgcn_mfma_f32_16x16x32_bf16(af, b2, acc2, 0, 0, 0);
        }
    }
    // ---- softmax over 48, keep 32; write aT bf16; per-wave asum partials ----
    {
        const float t0 = t_s[lr], t1 = t_s[16 + lr], t2 = t_s[32 + lr];
        float a0[4], a1[4];
        #pragma unroll
        for (int r = 0; r < 4; ++r) {
            float l0 = acc0[r] + t0, l1 = acc1[r] + t1, l2 = acc2[r] + t2;
            float m = fmaxf(fmaxf(l0, l1), l2);
            #pragma unroll
            for (int o = 1; o < 16; o <<= 1) m = fmaxf(m, __shfl_xor(m, o));
            float e0 = __expf(l0 - m), e1 = __expf(l1 - m), e2 = __expf(l2 - m);
            float s = e0 + e1 + e2;
            #pragma unroll
            for (int o = 1; o < 16; o <<= 1) s += __shfl_xor(s, o);
            float inv = 1.0f / s;
            a0[r] = e0 * inv; a1[r] = e1 * inv;
        }
        float p0 = 0.f, p1 = 0.f;
        #pragma unroll
        for (int r = 0; r < 4; ++r) {
            int n = wave * 16 + lg * 4 + r;
            aT[lr][n]      = f2bf(a0[r]);
            aT[16 + lr][n] = f2bf(a1[r]);
            p0 += a0[r]; p1 += a1[r];
        }
        p0 += __shfl_xor(p0, 16); p0 += __shfl_xor(p0, 32);
        p1 += __shfl_xor(p1, 16); p1 += __shfl_xor(p1, 32);
        if (lane < 16) { asum_part[wave][lane] = p0; asum_part[wave][16 + lane] = p1; }
    }
    __syncthreads();
    if (tid < KC) {
        float s = 0.f;
        #pragma unroll
        for (int w2 = 0; w2 < 8; ++w2) s += asum_part[w2][tid];
        asum_s[tid] = s;
    }

    // ---- phase 2: vlad[512][32] = x^T @ a ; wave w owns d-tiles w*4..w*4+3 ----
    f32x4 vacc[4][2];
    #pragma unroll
    for (int i = 0; i < 4; ++i) {
        vacc[i][0] = (f32x4){0.f,0.f,0.f,0.f};
        vacc[i][1] = (f32x4){0.f,0.f,0.f,0.f};
    }
    #pragma unroll
    for (int ns = 0; ns < 4; ++ns) {
        short8 b0 = *(const short8*)(&aT[lr][ns * 32 + lg * 8]);
        short8 b1 = *(const short8*)(&aT[16 + lr][ns * 32 + lg * 8]);
        #pragma unroll
        for (int dti = 0; dti < 4; ++dti) {
            const int d = (wave * 4 + dti) * 16 + lr;
            const int base = (ns * 32 + lg * 8) * 1024 + 2 * d;
            short8 af;
            #pragma unroll
            for (int j = 0; j < 8; ++j)
                af[j] = *(const short*)((const char*)xs + ((base + j * 1024) ^ (j << 4)));
            vacc[dti][0] = __builtin_amdgcn_mfma_f32_16x16x32_bf16(af, b0, vacc[dti][0], 0, 0, 0);
            vacc[dti][1] = __builtin_amdgcn_mfma_f32_16x16x32_bf16(af, b1, vacc[dti][1], 0, 0, 0);
        }
    }
    __syncthreads();   // asum_s ready; aT reads done

    // ---- epilogue: subtract asum*c2, column sumsq partials ----
    float vv[4][2][4];
    float cs0 = 0.f, cs1 = 0.f;
    const float as0 = asum_s[lr], as1 = asum_s[16 + lr];
    #pragma unroll
    for (int dti = 0; dti < 4; ++dti) {
        #pragma unroll
        for (int r = 0; r < 4; ++r) {
            int d = (wave * 4 + dti) * 16 + lg * 4 + r;
            float v0 = vacc[dti][0][r] - as0 * c2[d * KC + lr];
            float v1 = vacc[dti][1][r] - as1 * c2[d * KC + 16 + lr];
            vv[dti][0][r] = v0; vv[dti][1][r] = v1;
            cs0 += v0 * v0; cs1 += v1 * v1;
        }
    }
    cs0 += __shfl_xor(cs0, 16); cs0 += __shfl_xor(cs0, 32);
    cs1 += __shfl_xor(cs1, 16); cs1 += __shfl_xor(cs1, 32);
    if (lane < 16) { colsq_part[wave][lane] = cs0; colsq_part[wave][16 + lane] = cs1; }
    __syncthreads();
    if (tid < KC) {
        float sq = 0.f;
        #pragma unroll
        for (int w2 = 0; w2 < 8; ++w2) sq += colsq_part[w2][tid];
        float cn = sqrtf(sq);
        float s1 = 1.0f / fmaxf(cn, 1e-12f);
        float c1 = cn * s1;
        float tot = c1 * c1;
        #pragma unroll
        for (int o = 1; o < 32; o <<= 1) tot += __shfl_xor(tot, o);
        scalek[tid] = s1 * (1.0f / fmaxf(sqrtf(tot), 1e-12f));
    }
    __syncthreads();
    {
        float* ob = out + (size_t)b * (DIM * KC);
        const float sk0 = scalek[lr], sk1 = scalek[16 + lr];
        #pragma unroll
        for (int dti = 0; dti < 4; ++dti) {
            #pragma unroll
            for (int r = 0; r < 4; ++r) {
                int d = (wave * 4 + dti) * 16 + lg * 4 + r;
                ob[d * KC + lr]      = vv[dti][0][r] * sk0;
                ob[d * KC + 16 + lr] = vv[dti][1][r] * sk1;
            }
        }
    }
}

extern "C" void kernel_launch(void* const* d_in, const int* in_sizes, int n_in,
                              void* d_out, int out_size, void* d_ws, size_t ws_size,
                              hipStream_t stream) {
    const float* x        = (const float*)d_in[0];
    const float* clusters = (const float*)d_in[1];
    const float* bn_w     = (const float*)d_in[2];
    const float* bn_b     = (const float*)d_in[3];
    const float* bn_rm    = (const float*)d_in[4];
    const float* bn_rv    = (const float*)d_in[5];
    const float* c2       = (const float*)d_in[6];
    float* out = (float*)d_out;

    u16*   cTs  = (u16*)d_ws;
    float* tvec = (float*)((char*)d_ws + KT * DIM * sizeof(u16));

    const int B = in_sizes[0] / (NPT * DIM);

    prep_kernel<<<KT, 256, 0, stream>>>(clusters, bn_w, bn_b, bn_rm, bn_rv, cTs, tvec);
    vlad_kernel<<<B, 512, 0, stream>>>(x, c2, cTs, tvec, out);
}